// Round 2
// baseline (315.292 us; speedup 1.0000x reference)
//
#include <hip/hip_runtime.h>

#define LOGZERO (-1.0e10f)

constexpr int BS    = 16;
constexpr int XMAX  = 512;
constexpr int VOCAB = 4000;
constexpr int YMAX  = 64;
constexpr int PF    = 16;   // gather prefetch depth (reg ring), no barriers -> covers ~900cy HBM

// output layout (flat float32, reference return order)
constexpr size_t AS_OFF = 0;                                       // aligned_seq [16][512]
constexpr size_t TM_OFF = (size_t)BS * XMAX;                       // trigger_mask [16][65][512]
constexpr size_t YL_OFF = TM_OFF + (size_t)BS * (YMAX + 1) * XMAX; // ylens+1 [16]
constexpr size_t SC_OFF = YL_OFF + BS;                             // score [16]

__device__ __forceinline__ float dpp_shr1_f(float x, float fill) {
    // full-wave shift-down-by-1: lane i gets lane i-1's x; lane 0 gets `fill`
    return __int_as_float(__builtin_amdgcn_update_dpp(
        __float_as_int(fill), __float_as_int(x), 0x138 /*wave_shr:1*/, 0xF, 0xF, false));
}
__device__ __forceinline__ int dpp_shr1_i(int x, int fill) {
    return __builtin_amdgcn_update_dpp(fill, x, 0x138, 0xF, 0xF, false);
}

// backtrace one step at time T given mask regs A={bE,bO0}, Bv={bO1,bX}
#define BT(T, A, Bv) {                                                         \
    const int ct = ((T) == ss - 1) ? ist : cur;                                \
    states[(T)] = ((T) <= ss - 1) ? ct : 0;                                    \
    if ((T) >= 1 && (T) <= ss - 1) {                                           \
        const int h = ct >> 1;                                                 \
        int code;                                                              \
        if (ct == 128)      code = (int)((Bv.y >> 63) & 1ULL);                 \
        else if (ct & 1)    code = (int)((A.y  >> h) & 1ULL) |                 \
                                   ((int)((Bv.x >> h) & 1ULL) << 1);           \
        else                code = (int)((A.x  >> h) & 1ULL);                  \
        cur = ct - code;                                                       \
    } else cur = ct;                                                           \
}

__global__ __launch_bounds__(64)
void ctc_viterbi_kernel(const float* __restrict__ ctc,
                        const int* __restrict__ src_size,
                        const int* __restrict__ ys,
                        const int* __restrict__ ylens,
                        const int* __restrict__ blank_p,
                        float* __restrict__ out)
{
    const int b    = blockIdx.x;
    const int lane = threadIdx.x;          // 64 threads = 1 wave per batch element

    const int blank = blank_p[0];
    const int ss    = src_size[b];
    const int ylen  = ylens[b];
    const int plen  = 2 * ylen + 1;

    __shared__ ulonglong2 MA[XMAX];        // {ballot(evenSel), ballot(odd bit0)}
    __shared__ ulonglong2 MB[XMAX];        // {ballot(odd bit1), ballot(state128 sel)}
    __shared__ int states[XMAX];
    __shared__ int seq[XMAX];
    __shared__ int trig[XMAX];
    __shared__ int ysL[YMAX];

    // lane i owns states 2i (blank) and 2i+1 (label ys[i]); lane 63 also state 128 (blank)
    const int ysv = ys[b * YMAX + lane];
    ysL[lane] = ysv;
    const int  ysPrev = dpp_shr1_i(ysv, -1);
    const bool sameO  = (ysv == ysPrev);   // odd-state l-2 transition forbidden

    const float* pOdd = ctc + (size_t)b * XMAX * VOCAB + ysv;
    const float* pBl  = ctc + (size_t)b * XMAX * VOCAB + blank;

    const bool outE = (lane >  ylen);      // state 2i   >= plen
    const bool outO = (lane >= ylen);      // state 2i+1 >= plen
    const bool outX = (ylen <  YMAX);      // state 128  >= plen

    float rO[PF], rB[PF];
    #pragma unroll
    for (int k = 0; k < PF; ++k) {
        rO[k] = pOdd[(size_t)k * VOCAB];
        rB[k] = pBl [(size_t)k * VOCAB];
    }

    float aE = (lane == 0) ? 0.0f : LOGZERO;   // alpha[2i]
    float aO = LOGZERO;                        // alpha[2i+1]
    float aX = LOGZERO;                        // alpha[128] (lane 63)
    float fE = LOGZERO, fO = LOGZERO, fX = LOGZERO;

    for (int tb = 0; tb < XMAX; tb += PF) {
        #pragma unroll
        for (int k = 0; k < PF; ++k) {
            const int t = tb + k;
            const float lpO = (t < ss) ? rO[k] : LOGZERO;
            const float lpB = (t < ss) ? rB[k] : LOGZERO;
            if (t + PF < XMAX) {
                rO[k] = pOdd[(size_t)(t + PF) * VOCAB];
                rB[k] = pBl [(size_t)(t + PF) * VOCAB];
            }

            const float prevO = dpp_shr1_f(aO, LOGZERO);   // alpha[2i-1]

            // even state 2i: m0=aE, m1=prevO, m2=LOGZERO (blank==blank always "same")
            const bool  selE  = (prevO > aE);
            const float bestE = selE ? prevO : aE;

            // odd state 2i+1: m0=aO, m1=aE (own), m2=prevO unless same-label
            float bestO = aO; int idxO = 0;
            if (aE > bestO) { bestO = aE; idxO = 1; }
            const float m2 = sameO ? LOGZERO : prevO;
            if (m2 > bestO) { bestO = m2; idxO = 2; }

            // state 128 (lane 63 local): m0=aX, m1=aO, m2=LOGZERO
            const bool  selX  = (aO > aX);
            const float bestX = selX ? aO : aX;

            const unsigned long long bE  = __ballot(selE);
            const unsigned long long bO0 = __ballot(idxO & 1);
            const unsigned long long bO1 = __ballot(idxO >> 1);
            const unsigned long long bX  = __ballot(selX);

            const float nE = (outE ? LOGZERO : bestE) + lpB;
            const float nO = (outO ? LOGZERO : bestO) + lpO;
            const float nX = (outX ? LOGZERO : bestX) + lpB;

            if (lane == 0) {
                ulonglong2 va; va.x = bE;  va.y = bO0; MA[t] = va;
                ulonglong2 vb; vb.x = bO1; vb.y = bX;  MB[t] = vb;
            }
            if (t == ss - 1) { fE = nE; fO = nO; fX = nX; }
            aE = nE; aO = nO; aX = nX;
        }
    }

    // final-frame scores: s1 = alpha[plen-1] (even, lane=ylen or state128), s2 = alpha[plen-2] (odd, lane ylen-1)
    const float s1 = (ylen == YMAX) ? __shfl(fX, 63) : __shfl(fE, ylen);
    const float s2 = __shfl(fO, ylen - 1);

    if (lane == 0) {
        out[SC_OFF + b] = fmaxf(s1, s2);
        out[YL_OFF + b] = (float)(ylen + 1);
        const int ist = (s1 > s2) ? (plen - 1) : (plen - 2);
        int cur = 0;

        // 4-deep software-pipelined backtrace over LDS mask arrays (addresses known)
        ulonglong2 ca0 = MA[XMAX-1], ca1 = MA[XMAX-2], ca2 = MA[XMAX-3], ca3 = MA[XMAX-4];
        ulonglong2 cb0 = MB[XMAX-1], cb1 = MB[XMAX-2], cb2 = MB[XMAX-3], cb3 = MB[XMAX-4];
        for (int tg = XMAX - 1; tg >= 3; tg -= 4) {
            ulonglong2 na0, na1, na2, na3, nb0, nb1, nb2, nb3;
            const bool more = (tg >= 7);
            if (more) {
                na0 = MA[tg-4]; nb0 = MB[tg-4];
                na1 = MA[tg-5]; nb1 = MB[tg-5];
                na2 = MA[tg-6]; nb2 = MB[tg-6];
                na3 = MA[tg-7]; nb3 = MB[tg-7];
            }
            BT(tg,     ca0, cb0);
            BT(tg - 1, ca1, cb1);
            BT(tg - 2, ca2, cb2);
            BT(tg - 3, ca3, cb3);
            if (more) {
                ca0 = na0; cb0 = nb0; ca1 = na1; cb1 = nb1;
                ca2 = na2; cb2 = nb2; ca3 = na3; cb3 = nb3;
            }
        }
    }
    __syncthreads();

    // ---- states -> labels (lane owns 8 consecutive t) ----
    const int t8 = lane * 8;
    int sq[8];
    #pragma unroll
    for (int j = 0; j < 8; ++j) {
        const int st = states[t8 + j];
        sq[j] = (st & 1) ? ysL[st >> 1] : blank;
        seq[t8 + j] = sq[j];
    }
    __syncthreads();

    // collapse repeats vs ORIGINAL left neighbor (leading pad = 0)
    const int prevLast = (lane == 0) ? 0 : seq[t8 - 1];
    int cl[8];
    #pragma unroll
    for (int j = 0; j < 8; ++j) {
        const int pv = j ? sq[j - 1] : prevLast;
        cl[j] = (sq[j] == pv) ? 0 : sq[j];
    }

    // aligned_seq out (float4 x2)
    {
        float* as = out + AS_OFF + (size_t)b * XMAX + t8;
        float4 o0, o1;
        o0.x = (float)cl[0]; o0.y = (float)cl[1]; o0.z = (float)cl[2]; o0.w = (float)cl[3];
        o1.x = (float)cl[4]; o1.y = (float)cl[5]; o1.z = (float)cl[6]; o1.w = (float)cl[7];
        *(float4*)as = o0; *((float4*)as + 1) = o1;
    }

    // trig[t] = (0!=blank) + count(cl[0..t-1] != blank)  (inclusive cumsum of shifted-collapsed)
    int cnt = 0;
    #pragma unroll
    for (int j = 0; j < 8; ++j) cnt += (cl[j] != blank);
    int x = cnt;
    #pragma unroll
    for (int d = 1; d < 64; d <<= 1) {
        const int y = __shfl_up(x, d);
        if (lane >= d) x += y;
    }
    int run = x - cnt + ((0 != blank) ? 1 : 0);
    #pragma unroll
    for (int j = 0; j < 8; ++j) {
        trig[t8 + j] = run;
        run += (cl[j] != blank);
    }
    __syncthreads();

    // trigger mask: rows 0..63: trig==y ; row 64: (trig==64 && t<ss) || t==ss-1
    float* tm = out + TM_OFF + (size_t)b * (YMAX + 1) * XMAX;
    for (int i4 = lane * 4; i4 < (YMAX + 1) * XMAX; i4 += 64 * 4) {
        const int y  = i4 >> 9;
        const int t0 = i4 & (XMAX - 1);
        const int4 tg4 = *(const int4*)&trig[t0];
        float4 v;
        if (y == YMAX) {
            v.x = ((tg4.x == YMAX && (t0 + 0) < ss) || (t0 + 0) == ss - 1) ? 1.0f : 0.0f;
            v.y = ((tg4.y == YMAX && (t0 + 1) < ss) || (t0 + 1) == ss - 1) ? 1.0f : 0.0f;
            v.z = ((tg4.z == YMAX && (t0 + 2) < ss) || (t0 + 2) == ss - 1) ? 1.0f : 0.0f;
            v.w = ((tg4.w == YMAX && (t0 + 3) < ss) || (t0 + 3) == ss - 1) ? 1.0f : 0.0f;
        } else {
            v.x = (tg4.x == y) ? 1.0f : 0.0f;
            v.y = (tg4.y == y) ? 1.0f : 0.0f;
            v.z = (tg4.z == y) ? 1.0f : 0.0f;
            v.w = (tg4.w == y) ? 1.0f : 0.0f;
        }
        *(float4*)(tm + i4) = v;
    }
}

extern "C" void kernel_launch(void* const* d_in, const int* in_sizes, int n_in,
                              void* d_out, int out_size, void* d_ws, size_t ws_size,
                              hipStream_t stream) {
    (void)in_sizes; (void)n_in; (void)d_ws; (void)ws_size; (void)out_size;
    const float* ctc      = (const float*)d_in[0];
    // d_in[1] = src_mask — derivable from src_size, unused
    const int*   src_size = (const int*)d_in[2];
    const int*   ys       = (const int*)d_in[3];
    const int*   ylens    = (const int*)d_in[4];
    const int*   blank    = (const int*)d_in[5];
    float*       out      = (float*)d_out;

    ctc_viterbi_kernel<<<BS, 64, 0, stream>>>(ctc, src_size, ys, ylens, blank, out);
}

// Round 3
// 163.655 us; speedup vs baseline: 1.9266x; 1.9266x over previous
//
#include <hip/hip_runtime.h>

#define LOGZERO (-1.0e10f)

constexpr int BS    = 16;
constexpr int XMAX  = 512;
constexpr int VOCAB = 4000;
constexpr int YMAX  = 64;
constexpr int PF    = 16;   // DP prefetch depth (reg ring), unconditional loads
constexpr int TCH   = 16;   // time-steps per gather block

// output layout (flat float32, reference return order)
constexpr size_t AS_OFF = 0;                                       // aligned_seq [16][512]
constexpr size_t TM_OFF = (size_t)BS * XMAX;                       // trigger_mask [16][65][512]
constexpr size_t YL_OFF = TM_OFF + (size_t)BS * (YMAX + 1) * XMAX; // ylens+1 [16]
constexpr size_t SC_OFF = YL_OFF + BS;                             // score [16]
// scratch aliasing: lpp[b][t][j] (j=0..63 odd labels) lives at TM_OFF + b*65*512 + t*65 + j
//                   blank lpp[b][t]                  lives at AS_OFF + b*512 + t
// kernel2 consumes these BEFORE writing the real outputs over them.

__device__ __forceinline__ float dpp_shr1_f(float x, float fill) {
    // full-wave shift-down-by-1: lane i gets lane i-1's x; lane 0 gets `fill`
    return __int_as_float(__builtin_amdgcn_update_dpp(
        __float_as_int(fill), __float_as_int(x), 0x138 /*wave_shr:1*/, 0xF, 0xF, false));
}
__device__ __forceinline__ int dpp_shr1_i(int x, int fill) {
    return __builtin_amdgcn_update_dpp(fill, x, 0x138, 0xF, 0xF, false);
}

// ---------------- kernel 1: parallel gather of per-path log-probs ----------------
__global__ __launch_bounds__(64)
void gather_kernel(const float* __restrict__ ctc,
                   const int* __restrict__ ys,
                   const int* __restrict__ blank_p,
                   float* __restrict__ out)
{
    const int tc   = blockIdx.x;           // 0..31 time chunk
    const int b    = blockIdx.y;           // 0..15 batch
    const int lane = threadIdx.x;

    const int blank = blank_p[0];
    const int ysv   = ys[b * YMAX + lane];

    const float* base = ctc + ((size_t)b * XMAX + (size_t)tc * TCH) * VOCAB;

    // 16 divergent gathers issued back-to-back (64 lines each) — concurrency via 512 blocks
    float v[TCH];
    #pragma unroll
    for (int j = 0; j < TCH; ++j)
        v[j] = base[(size_t)j * VOCAB + ysv];
    // blank column for the chunk's 16 t's (lanes 0..15 meaningful)
    const float bl = base[(size_t)(lane & (TCH - 1)) * VOCAB + blank];

    float* lpp = out + TM_OFF + (size_t)b * (YMAX + 1) * XMAX + (size_t)tc * TCH * 65;
    #pragma unroll
    for (int j = 0; j < TCH; ++j)
        lpp[(size_t)j * 65 + lane] = v[j];
    if (lane < TCH)
        out[AS_OFF + (size_t)b * XMAX + (size_t)tc * TCH + lane] = bl;
}

// backtrace one step at time T given mask regs A={bE,bO0}, Bv={bO1,bX}
#define BT(T, A, Bv) {                                                         \
    const int ct = ((T) == ss - 1) ? ist : cur;                                \
    states[(T)] = ((T) <= ss - 1) ? ct : 0;                                    \
    if ((T) >= 1 && (T) <= ss - 1) {                                           \
        const int h = ct >> 1;                                                 \
        int code;                                                              \
        if (ct == 128)      code = (int)((Bv.y >> 63) & 1ULL);                 \
        else if (ct & 1)    code = (int)((A.y  >> h) & 1ULL) |                 \
                                   ((int)((Bv.x >> h) & 1ULL) << 1);           \
        else                code = (int)((A.x  >> h) & 1ULL);                  \
        cur = ct - code;                                                       \
    } else cur = ct;                                                           \
}

// ---------------- kernel 2: sequential Viterbi DP + backtrace + outputs ----------------
__global__ __launch_bounds__(64)
void ctc_viterbi_kernel(const int* __restrict__ src_size,
                        const int* __restrict__ ys,
                        const int* __restrict__ ylens,
                        const int* __restrict__ blank_p,
                        float* __restrict__ out)
{
    const int b    = blockIdx.x;
    const int lane = threadIdx.x;          // 1 wave per batch element

    const int blank = blank_p[0];
    const int ss    = src_size[b];
    const int ylen  = ylens[b];
    const int plen  = 2 * ylen + 1;

    __shared__ ulonglong2 MA[XMAX];        // {ballot(evenSel), ballot(odd bit0)}
    __shared__ ulonglong2 MB[XMAX];        // {ballot(odd bit1), ballot(state128 sel)}
    __shared__ int states[XMAX];
    __shared__ int seq[XMAX];
    __shared__ int trig[XMAX];
    __shared__ int ysL[YMAX];

    // lane i owns states 2i (blank) and 2i+1 (label ys[i]); lane 63 also state 128 (blank)
    const int ysv = ys[b * YMAX + lane];
    ysL[lane] = ysv;
    const int  ysPrev = dpp_shr1_i(ysv, -1);
    const bool sameO  = (ysv == ysPrev);   // odd-state l-2 transition forbidden

    const float* lpp = out + TM_OFF + (size_t)b * (YMAX + 1) * XMAX;  // [t][j], stride 65
    const float* bls = out + AS_OFF + (size_t)b * XMAX;               // blank lpp [t]

    const bool outE = (lane >  ylen);      // state 2i   >= plen
    const bool outO = (lane >= ylen);      // state 2i+1 >= plen
    const bool outX = (ylen <  YMAX);      // state 128  >= plen

    // unconditional prefetch ring (contiguous per-t reads, L2/L3-resident)
    float rO[PF], rB[PF];
    #pragma unroll
    for (int k = 0; k < PF; ++k) {
        rO[k] = lpp[(size_t)k * 65 + lane];
        rB[k] = bls[k];
    }

    float aE = (lane == 0) ? 0.0f : LOGZERO;   // alpha[2i]
    float aO = LOGZERO;                        // alpha[2i+1]
    float aX = LOGZERO;                        // alpha[128] (lane 63)
    float fE = LOGZERO, fO = LOGZERO, fX = LOGZERO;

    for (int tb = 0; tb < XMAX; tb += PF) {
        #pragma unroll
        for (int k = 0; k < PF; ++k) {
            const int t = tb + k;
            const float lpO = (t < ss) ? rO[k] : LOGZERO;
            const float lpB = (t < ss) ? rB[k] : LOGZERO;

            // UNCONDITIONAL clamped prefetch -> statically countable vmcnt
            int rowt = t + PF; rowt = (rowt < XMAX) ? rowt : (XMAX - 1);
            rO[k] = lpp[(size_t)rowt * 65 + lane];
            rB[k] = bls[rowt];

            const float prevO = dpp_shr1_f(aO, LOGZERO);   // alpha[2i-1]

            // even state 2i: m0=aE, m1=prevO, m2=LOGZERO (blank==blank always "same")
            const bool  selE  = (prevO > aE);
            const float bestE = selE ? prevO : aE;

            // odd state 2i+1: m0=aO, m1=aE (own), m2=prevO unless same-label
            float bestO = aO; int idxO = 0;
            if (aE > bestO) { bestO = aE; idxO = 1; }
            const float m2 = sameO ? LOGZERO : prevO;
            if (m2 > bestO) { bestO = m2; idxO = 2; }

            // state 128 (lane 63 local): m0=aX, m1=aO, m2=LOGZERO
            const bool  selX  = (aO > aX);
            const float bestX = selX ? aO : aX;

            const unsigned long long bE  = __ballot(selE);
            const unsigned long long bO0 = __ballot(idxO & 1);
            const unsigned long long bO1 = __ballot(idxO >> 1);
            const unsigned long long bX  = __ballot(selX);

            const float nE = (outE ? LOGZERO : bestE) + lpB;
            const float nO = (outO ? LOGZERO : bestO) + lpO;
            const float nX = (outX ? LOGZERO : bestX) + lpB;

            if (lane == 0) {
                ulonglong2 va; va.x = bE;  va.y = bO0; MA[t] = va;
                ulonglong2 vb; vb.x = bO1; vb.y = bX;  MB[t] = vb;
            }
            if (t == ss - 1) { fE = nE; fO = nO; fX = nX; }
            aE = nE; aO = nO; aX = nX;
        }
    }

    // final-frame scores: s1 = alpha[plen-1], s2 = alpha[plen-2]
    const float s1 = (ylen == YMAX) ? __shfl(fX, 63) : __shfl(fE, ylen);
    const float s2 = __shfl(fO, ylen - 1);

    if (lane == 0) {
        out[SC_OFF + b] = fmaxf(s1, s2);
        out[YL_OFF + b] = (float)(ylen + 1);
        const int ist = (s1 > s2) ? (plen - 1) : (plen - 2);
        int cur = 0;

        // 4-deep software-pipelined backtrace over LDS mask arrays
        ulonglong2 ca0 = MA[XMAX-1], ca1 = MA[XMAX-2], ca2 = MA[XMAX-3], ca3 = MA[XMAX-4];
        ulonglong2 cb0 = MB[XMAX-1], cb1 = MB[XMAX-2], cb2 = MB[XMAX-3], cb3 = MB[XMAX-4];
        for (int tg = XMAX - 1; tg >= 3; tg -= 4) {
            ulonglong2 na0, na1, na2, na3, nb0, nb1, nb2, nb3;
            const bool more = (tg >= 7);
            if (more) {
                na0 = MA[tg-4]; nb0 = MB[tg-4];
                na1 = MA[tg-5]; nb1 = MB[tg-5];
                na2 = MA[tg-6]; nb2 = MB[tg-6];
                na3 = MA[tg-7]; nb3 = MB[tg-7];
            }
            BT(tg,     ca0, cb0);
            BT(tg - 1, ca1, cb1);
            BT(tg - 2, ca2, cb2);
            BT(tg - 3, ca3, cb3);
            if (more) {
                ca0 = na0; cb0 = nb0; ca1 = na1; cb1 = nb1;
                ca2 = na2; cb2 = nb2; ca3 = na3; cb3 = nb3;
            }
        }
    }
    __syncthreads();

    // ---- states -> labels (lane owns 8 consecutive t) ----
    const int t8 = lane * 8;
    int sq[8];
    #pragma unroll
    for (int j = 0; j < 8; ++j) {
        const int st = states[t8 + j];
        sq[j] = (st & 1) ? ysL[st >> 1] : blank;
        seq[t8 + j] = sq[j];
    }
    __syncthreads();

    // collapse repeats vs ORIGINAL left neighbor (leading pad = 0)
    const int prevLast = (lane == 0) ? 0 : seq[t8 - 1];
    int cl[8];
    #pragma unroll
    for (int j = 0; j < 8; ++j) {
        const int pv = j ? sq[j - 1] : prevLast;
        cl[j] = (sq[j] == pv) ? 0 : sq[j];
    }

    // aligned_seq out (overwrites blank-lpp scratch; DP already consumed it)
    {
        float* as = out + AS_OFF + (size_t)b * XMAX + t8;
        float4 o0, o1;
        o0.x = (float)cl[0]; o0.y = (float)cl[1]; o0.z = (float)cl[2]; o0.w = (float)cl[3];
        o1.x = (float)cl[4]; o1.y = (float)cl[5]; o1.z = (float)cl[6]; o1.w = (float)cl[7];
        *(float4*)as = o0; *((float4*)as + 1) = o1;
    }

    // trig[t] = count of shifted-collapsed != blank (inclusive cumsum of shift)
    int cnt = 0;
    #pragma unroll
    for (int j = 0; j < 8; ++j) cnt += (cl[j] != blank);
    int x = cnt;
    #pragma unroll
    for (int d = 1; d < 64; d <<= 1) {
        const int y = __shfl_up(x, d);
        if (lane >= d) x += y;
    }
    int run = x - cnt + ((0 != blank) ? 1 : 0);
    #pragma unroll
    for (int j = 0; j < 8; ++j) {
        trig[t8 + j] = run;
        run += (cl[j] != blank);
    }
    __syncthreads();

    // trigger mask (overwrites lpp scratch): rows 0..63: trig==y ; row 64 special
    float* tm = out + TM_OFF + (size_t)b * (YMAX + 1) * XMAX;
    for (int i4 = lane * 4; i4 < (YMAX + 1) * XMAX; i4 += 64 * 4) {
        const int y  = i4 >> 9;
        const int t0 = i4 & (XMAX - 1);
        const int4 tg4 = *(const int4*)&trig[t0];
        float4 v;
        if (y == YMAX) {
            v.x = ((tg4.x == YMAX && (t0 + 0) < ss) || (t0 + 0) == ss - 1) ? 1.0f : 0.0f;
            v.y = ((tg4.y == YMAX && (t0 + 1) < ss) || (t0 + 1) == ss - 1) ? 1.0f : 0.0f;
            v.z = ((tg4.z == YMAX && (t0 + 2) < ss) || (t0 + 2) == ss - 1) ? 1.0f : 0.0f;
            v.w = ((tg4.w == YMAX && (t0 + 3) < ss) || (t0 + 3) == ss - 1) ? 1.0f : 0.0f;
        } else {
            v.x = (tg4.x == y) ? 1.0f : 0.0f;
            v.y = (tg4.y == y) ? 1.0f : 0.0f;
            v.z = (tg4.z == y) ? 1.0f : 0.0f;
            v.w = (tg4.w == y) ? 1.0f : 0.0f;
        }
        *(float4*)(tm + i4) = v;
    }
}

extern "C" void kernel_launch(void* const* d_in, const int* in_sizes, int n_in,
                              void* d_out, int out_size, void* d_ws, size_t ws_size,
                              hipStream_t stream) {
    (void)in_sizes; (void)n_in; (void)d_ws; (void)ws_size; (void)out_size;
    const float* ctc      = (const float*)d_in[0];
    // d_in[1] = src_mask — derivable from src_size, unused
    const int*   src_size = (const int*)d_in[2];
    const int*   ys       = (const int*)d_in[3];
    const int*   ylens    = (const int*)d_in[4];
    const int*   blank    = (const int*)d_in[5];
    float*       out      = (float*)d_out;

    dim3 g1(XMAX / TCH, BS);
    gather_kernel<<<g1, 64, 0, stream>>>(ctc, ys, blank, out);
    ctc_viterbi_kernel<<<BS, 64, 0, stream>>>(src_size, ys, ylens, blank, out);
}

// Round 4
// 157.087 us; speedup vs baseline: 2.0071x; 1.0418x over previous
//
#include <hip/hip_runtime.h>

#define LOGZERO (-1.0e10f)

constexpr int BS    = 16;
constexpr int XMAX  = 512;
constexpr int VOCAB = 4000;
constexpr int YMAX  = 64;
constexpr int PF    = 8;    // DP prefetch ring depth over LDS
constexpr int TCH   = 8;    // time-steps per gather block (1024 blocks total)

// output layout (flat float32, reference return order)
constexpr size_t AS_OFF = 0;                                       // aligned_seq [16][512]
constexpr size_t TM_OFF = (size_t)BS * XMAX;                       // trigger_mask [16][65][512]
constexpr size_t YL_OFF = TM_OFF + (size_t)BS * (YMAX + 1) * XMAX; // ylens+1 [16]
constexpr size_t SC_OFF = YL_OFF + BS;                             // score [16]
// scratch aliasing: packed lpp[b][t][j] (j=0..63 odd labels, j=64 blank) lives in the
// TM region at TM_OFF + b*65*512 + t*65 + j. Kernel 2 copies it to LDS before
// overwriting the region with the real trigger_mask.

__device__ __forceinline__ float dpp_shr1_f(float x, float fill) {
    // full-wave shift-down-by-1: lane i gets lane i-1's x; lane 0 gets `fill`
    return __int_as_float(__builtin_amdgcn_update_dpp(
        __float_as_int(fill), __float_as_int(x), 0x138 /*wave_shr:1*/, 0xF, 0xF, false));
}
__device__ __forceinline__ int dpp_shr1_i(int x, int fill) {
    return __builtin_amdgcn_update_dpp(fill, x, 0x138, 0xF, 0xF, false);
}

// ---------------- kernel 1: parallel gather of per-path log-probs ----------------
__global__ __launch_bounds__(64)
void gather_kernel(const float* __restrict__ ctc,
                   const int* __restrict__ ys,
                   const int* __restrict__ blank_p,
                   float* __restrict__ out)
{
    const int tc   = blockIdx.x;           // time chunk (XMAX/TCH chunks)
    const int b    = blockIdx.y;           // batch
    const int lane = threadIdx.x;

    const int blank = blank_p[0];
    const int ysv   = ys[b * YMAX + lane];

    const float* base = ctc + ((size_t)b * XMAX + (size_t)tc * TCH) * VOCAB;

    float v[TCH];
    #pragma unroll
    for (int j = 0; j < TCH; ++j)
        v[j] = base[(size_t)j * VOCAB + ysv];
    const float bl = base[(size_t)(lane & (TCH - 1)) * VOCAB + blank];

    float* lpp = out + TM_OFF + (size_t)b * (YMAX + 1) * XMAX + (size_t)tc * TCH * 65;
    #pragma unroll
    for (int j = 0; j < TCH; ++j)
        lpp[(size_t)j * 65 + lane] = v[j];
    if (lane < TCH)
        lpp[(size_t)lane * 65 + 64] = bl;   // blank goes in column 64 (packed rows)
}

// backtrace one step at time T given mask regs A={bE,bO0}, Bv={bO1,bX}
#define BT(T, A, Bv) {                                                         \
    const int ct = ((T) == ss - 1) ? ist : cur;                                \
    states[(T)] = ((T) <= ss - 1) ? ct : 0;                                    \
    if ((T) >= 1 && (T) <= ss - 1) {                                           \
        const int h = ct >> 1;                                                 \
        int code;                                                              \
        if (ct == 128)      code = (int)((Bv.y >> 63) & 1ULL);                 \
        else if (ct & 1)    code = (int)((A.y  >> h) & 1ULL) |                 \
                                   ((int)((Bv.x >> h) & 1ULL) << 1);           \
        else                code = (int)((A.x  >> h) & 1ULL);                  \
        cur = ct - code;                                                       \
    } else cur = ct;                                                           \
}

// ---------------- kernel 2: LDS-staged sequential Viterbi DP + outputs ----------------
__global__ __launch_bounds__(256)
void ctc_viterbi_kernel(const int* __restrict__ src_size,
                        const int* __restrict__ ys,
                        const int* __restrict__ ylens,
                        const int* __restrict__ blank_p,
                        float* __restrict__ out)
{
    const int b    = blockIdx.x;
    const int tid  = threadIdx.x;          // 256 threads; wave 0 runs the DP
    const int lane = tid & 63;

    const int blank = blank_p[0];
    const int ss    = src_size[b];
    const int ylen  = ylens[b];
    const int plen  = 2 * ylen + 1;

    __shared__ __align__(16) float lppL[XMAX * 65];   // 133 KB packed lpp table
    __shared__ ulonglong2 MA[XMAX];        // {ballot(evenSel), ballot(odd bit0)}
    __shared__ ulonglong2 MB[XMAX];        // {ballot(odd bit1), ballot(state128 sel)}
    __shared__ int states[XMAX];
    __shared__ int trig[XMAX];
    __shared__ int ysL[YMAX];

    // ---- phase 0: bulk copy the packed table into LDS (all 4 waves) ----
    {
        const float4* src = (const float4*)(out + TM_OFF + (size_t)b * (YMAX + 1) * XMAX);
        float4* dst = (float4*)lppL;
        #pragma unroll 4
        for (int i = tid; i < XMAX * 65 / 4; i += 256)
            dst[i] = src[i];
    }
    const int ysv = ys[b * YMAX + lane];
    if (tid < YMAX) ysL[tid] = ys[b * YMAX + tid];
    __syncthreads();

    // ---- phase 1: wave 0 runs the sequential DP + backtrace ----
    if (tid < 64) {
        const int  ysPrev = dpp_shr1_i(ysv, -1);
        const bool sameO  = (ysv == ysPrev);   // odd-state l-2 transition forbidden

        const bool outE = (lane >  ylen);      // state 2i   >= plen
        const bool outO = (lane >= ylen);      // state 2i+1 >= plen
        const bool outX = (ylen <  YMAX);      // state 128  >= plen

        float rO[PF], rB[PF];
        #pragma unroll
        for (int k = 0; k < PF; ++k) {
            rO[k] = lppL[k * 65 + lane];
            rB[k] = lppL[k * 65 + 64];         // uniform address -> broadcast
        }

        float aE = (lane == 0) ? 0.0f : LOGZERO;   // alpha[2i]
        float aO = LOGZERO;                        // alpha[2i+1]
        float aX = LOGZERO;                        // alpha[128] (lane 63)
        float fE = LOGZERO, fO = LOGZERO, fX = LOGZERO;

        for (int tb = 0; tb < XMAX; tb += PF) {
            #pragma unroll
            for (int k = 0; k < PF; ++k) {
                const int t = tb + k;
                const float lpO = (t < ss) ? rO[k] : LOGZERO;
                const float lpB = (t < ss) ? rB[k] : LOGZERO;

                // unconditional clamped prefetch from LDS
                int rowt = t + PF; rowt = (rowt < XMAX) ? rowt : (XMAX - 1);
                rO[k] = lppL[rowt * 65 + lane];
                rB[k] = lppL[rowt * 65 + 64];

                const float prevO = dpp_shr1_f(aO, LOGZERO);   // alpha[2i-1]

                // even state 2i: m0=aE, m1=prevO, m2 always forbidden (blank==blank)
                const bool  selE  = (prevO > aE);
                const float bestE = selE ? prevO : aE;

                // odd state 2i+1: m0=aO, m1=aE (own), m2=prevO unless same-label
                float bestO = aO; int idxO = 0;
                if (aE > bestO) { bestO = aE; idxO = 1; }
                const float m2 = sameO ? LOGZERO : prevO;
                if (m2 > bestO) { bestO = m2; idxO = 2; }

                // state 128 (lane 63 local): m0=aX, m1=aO
                const bool  selX  = (aO > aX);
                const float bestX = selX ? aO : aX;

                const unsigned long long bE  = __ballot(selE);
                const unsigned long long bO0 = __ballot(idxO & 1);
                const unsigned long long bO1 = __ballot(idxO >> 1);
                const unsigned long long bX  = __ballot(selX);

                const float nE = (outE ? LOGZERO : bestE) + lpB;
                const float nO = (outO ? LOGZERO : bestO) + lpO;
                const float nX = (outX ? LOGZERO : bestX) + lpB;

                if (lane == 0) {
                    ulonglong2 va; va.x = bE;  va.y = bO0; MA[t] = va;
                    ulonglong2 vb; vb.x = bO1; vb.y = bX;  MB[t] = vb;
                }
                if (t == ss - 1) { fE = nE; fO = nO; fX = nX; }
                aE = nE; aO = nO; aX = nX;
            }
        }

        // final-frame scores: s1 = alpha[plen-1], s2 = alpha[plen-2]
        const float s1 = (ylen == YMAX) ? __shfl(fX, 63) : __shfl(fE, ylen);
        const float s2 = __shfl(fO, ylen - 1);

        if (lane == 0) {
            out[SC_OFF + b] = fmaxf(s1, s2);
            out[YL_OFF + b] = (float)(ylen + 1);
            const int ist = (s1 > s2) ? (plen - 1) : (plen - 2);
            int cur = 0;

            // 4-deep software-pipelined backtrace over LDS mask arrays
            ulonglong2 ca0 = MA[XMAX-1], ca1 = MA[XMAX-2], ca2 = MA[XMAX-3], ca3 = MA[XMAX-4];
            ulonglong2 cb0 = MB[XMAX-1], cb1 = MB[XMAX-2], cb2 = MB[XMAX-3], cb3 = MB[XMAX-4];
            for (int tg = XMAX - 1; tg >= 3; tg -= 4) {
                ulonglong2 na0, na1, na2, na3, nb0, nb1, nb2, nb3;
                const bool more = (tg >= 7);
                if (more) {
                    na0 = MA[tg-4]; nb0 = MB[tg-4];
                    na1 = MA[tg-5]; nb1 = MB[tg-5];
                    na2 = MA[tg-6]; nb2 = MB[tg-6];
                    na3 = MA[tg-7]; nb3 = MB[tg-7];
                }
                BT(tg,     ca0, cb0);
                BT(tg - 1, ca1, cb1);
                BT(tg - 2, ca2, cb2);
                BT(tg - 3, ca3, cb3);
                if (more) {
                    ca0 = na0; cb0 = nb0; ca1 = na1; cb1 = nb1;
                    ca2 = na2; cb2 = nb2; ca3 = na3; cb3 = nb3;
                }
            }
        }
    }
    __syncthreads();

    // ---- phase 2 (wave 0): states -> labels, collapse, aligned_seq, trig scan ----
    if (tid < 64) {
        const int t8 = lane * 8;
        int sq[8];
        #pragma unroll
        for (int j = 0; j < 8; ++j) {
            const int st = states[t8 + j];
            sq[j] = (st & 1) ? ysL[st >> 1] : blank;
        }
        const int lastv = sq[7];
        int prevLast = __shfl_up(lastv, 1);
        if (lane == 0) prevLast = 0;

        int cl[8];
        #pragma unroll
        for (int j = 0; j < 8; ++j) {
            const int pv = j ? sq[j - 1] : prevLast;
            cl[j] = (sq[j] == pv) ? 0 : sq[j];
        }

        {   // aligned_seq out
            float* as = out + AS_OFF + (size_t)b * XMAX + t8;
            float4 o0, o1;
            o0.x = (float)cl[0]; o0.y = (float)cl[1]; o0.z = (float)cl[2]; o0.w = (float)cl[3];
            o1.x = (float)cl[4]; o1.y = (float)cl[5]; o1.z = (float)cl[6]; o1.w = (float)cl[7];
            *(float4*)as = o0; *((float4*)as + 1) = o1;
        }

        // trig[t] = inclusive cumsum of shifted collapsed != blank
        int cnt = 0;
        #pragma unroll
        for (int j = 0; j < 8; ++j) cnt += (cl[j] != blank);
        int x = cnt;
        #pragma unroll
        for (int d = 1; d < 64; d <<= 1) {
            const int y = __shfl_up(x, d);
            if (lane >= d) x += y;
        }
        int run = x - cnt + ((0 != blank) ? 1 : 0);
        #pragma unroll
        for (int j = 0; j < 8; ++j) {
            trig[t8 + j] = run;
            run += (cl[j] != blank);
        }
    }
    __syncthreads();

    // ---- phase 3 (all 256): trigger mask overwrites the lpp scratch region ----
    float* tm = out + TM_OFF + (size_t)b * (YMAX + 1) * XMAX;
    for (int i4 = tid * 4; i4 < (YMAX + 1) * XMAX; i4 += 256 * 4) {
        const int y  = i4 >> 9;
        const int t0 = i4 & (XMAX - 1);
        const int4 tg4 = *(const int4*)&trig[t0];
        float4 v;
        if (y == YMAX) {
            v.x = ((tg4.x == YMAX && (t0 + 0) < ss) || (t0 + 0) == ss - 1) ? 1.0f : 0.0f;
            v.y = ((tg4.y == YMAX && (t0 + 1) < ss) || (t0 + 1) == ss - 1) ? 1.0f : 0.0f;
            v.z = ((tg4.z == YMAX && (t0 + 2) < ss) || (t0 + 2) == ss - 1) ? 1.0f : 0.0f;
            v.w = ((tg4.w == YMAX && (t0 + 3) < ss) || (t0 + 3) == ss - 1) ? 1.0f : 0.0f;
        } else {
            v.x = (tg4.x == y) ? 1.0f : 0.0f;
            v.y = (tg4.y == y) ? 1.0f : 0.0f;
            v.z = (tg4.z == y) ? 1.0f : 0.0f;
            v.w = (tg4.w == y) ? 1.0f : 0.0f;
        }
        *(float4*)(tm + i4) = v;
    }
}

extern "C" void kernel_launch(void* const* d_in, const int* in_sizes, int n_in,
                              void* d_out, int out_size, void* d_ws, size_t ws_size,
                              hipStream_t stream) {
    (void)in_sizes; (void)n_in; (void)d_ws; (void)ws_size; (void)out_size;
    const float* ctc      = (const float*)d_in[0];
    // d_in[1] = src_mask — derivable from src_size, unused
    const int*   src_size = (const int*)d_in[2];
    const int*   ys       = (const int*)d_in[3];
    const int*   ylens    = (const int*)d_in[4];
    const int*   blank    = (const int*)d_in[5];
    float*       out      = (float*)d_out;

    dim3 g1(XMAX / TCH, BS);
    gather_kernel<<<g1, 64, 0, stream>>>(ctc, ys, blank, out);
    ctc_viterbi_kernel<<<BS, 256, 0, stream>>>(src_size, ys, ylens, blank, out);
}

// Round 5
// 151.128 us; speedup vs baseline: 2.0863x; 1.0394x over previous
//
#include <hip/hip_runtime.h>

#define LOGZERO (-1.0e10f)

constexpr int BS    = 16;
constexpr int XMAX  = 512;
constexpr int VOCAB = 4000;
constexpr int YMAX  = 64;
constexpr int PF    = 6;    // LDS ring depth: 2*(PF-1)=10 outstanding lgkm, encodeable
constexpr int TCH   = 8;    // time-steps per gather block

// output layout (flat float32, reference return order)
constexpr size_t AS_OFF = 0;                                       // aligned_seq [16][512]
constexpr size_t TM_OFF = (size_t)BS * XMAX;                       // trigger_mask [16][65][512]
constexpr size_t YL_OFF = TM_OFF + (size_t)BS * (YMAX + 1) * XMAX; // ylens+1 [16]
constexpr size_t SC_OFF = YL_OFF + BS;                             // score [16]
// Scratch aliasing inside the per-batch TM region (65*512 floats = 133 KB):
//   phase A (gather): packed lpp[t][j], j=0..63 odd labels, j=64 blank, row stride 65
//   phase B (dp): after lpp is copied to LDS the region is dead; reused for
//     bp masks  : bytes [0, 512*32)   — per t: {bE, s1m, s2m, bX} (4 u64, 16B-aligned)
//     states    : bytes [16384, +2048) as int[512]
//   phase C (epilogue): whole region overwritten with the real trigger_mask.

__device__ __forceinline__ float dpp_shr1_f(float x, float fill) {
    // full-wave shift-down-by-1: lane i gets lane i-1's x; lane 0 gets `fill`
    return __int_as_float(__builtin_amdgcn_update_dpp(
        __float_as_int(fill), __float_as_int(x), 0x138 /*wave_shr:1*/, 0xF, 0xF, false));
}
__device__ __forceinline__ int dpp_shr1_i(int x, int fill) {
    return __builtin_amdgcn_update_dpp(fill, x, 0x138, 0xF, 0xF, false);
}

// ---------------- kernel 1: parallel gather of per-path log-probs ----------------
__global__ __launch_bounds__(64)
void gather_kernel(const float* __restrict__ ctc,
                   const int* __restrict__ ys,
                   const int* __restrict__ blank_p,
                   float* __restrict__ out)
{
    const int tc   = blockIdx.x;           // time chunk
    const int b    = blockIdx.y;           // batch
    const int lane = threadIdx.x;

    const int blank = blank_p[0];
    const int ysv   = ys[b * YMAX + lane];

    const float* base = ctc + ((size_t)b * XMAX + (size_t)tc * TCH) * VOCAB;

    float v[TCH];
    #pragma unroll
    for (int j = 0; j < TCH; ++j)
        v[j] = base[(size_t)j * VOCAB + ysv];
    const float bl = base[(size_t)(lane & (TCH - 1)) * VOCAB + blank];

    float* lpp = out + TM_OFF + (size_t)b * (YMAX + 1) * XMAX + (size_t)tc * TCH * 65;
    #pragma unroll
    for (int j = 0; j < TCH; ++j)
        lpp[(size_t)j * 65 + lane] = v[j];
    if (lane < TCH)
        lpp[(size_t)lane * 65 + 64] = bl;   // blank in column 64
}

// backtrace one step at time T; A={bE,s1m}, Bv={s2m,bX}
#define BT(T, A, Bv) {                                                         \
    const int ct = ((T) == ss - 1) ? ist : cur;                                \
    states[(T)] = ((T) <= ss - 1) ? ct : 0;                                    \
    int code = 0;                                                              \
    if ((T) >= 1 && (T) <= ss - 1) {                                           \
        if (ct == 128)      code = (int)((Bv.y >> 63) & 1ULL);                 \
        else if (ct & 1) {  const int h = ct >> 1;                             \
            code = ((Bv.x >> h) & 1ULL) ? 2 : (int)((A.y >> h) & 1ULL); }      \
        else                code = (int)((A.x >> (ct >> 1)) & 1ULL);           \
    }                                                                          \
    cur = ct - code;                                                           \
}

// one DP time-step; K is a compile-time ring index
#define DP_BODY(K)                                                             \
{                                                                              \
    const float lpO = rO[K], lpB = rB[K];                                      \
    rO[K] = lppL[offO]; rB[K] = lppL[offB]; offO += 65; offB += 65;            \
    const float prevO = dpp_shr1_f(aO, LOGZERO);                               \
    const float m2v   = sameO ? LOGZERO : prevO;                               \
    const float b01   = fmaxf(aO, aE);                                         \
    const unsigned long long bE  = __ballot(prevO > aE);                       \
    const unsigned long long s1m = __ballot(aE > aO);                          \
    const unsigned long long s2m = __ballot(m2v > b01);                        \
    const unsigned long long bX  = __ballot(aO > aX);                          \
    aX = fmaxf(aX, aO) + lpB;                                                  \
    aO = fmaxf(b01, m2v) + lpO;                                                \
    aE = fmaxf(aE, prevO) + lpB;                                               \
    if (lane == 0) {                                                           \
        ulonglong2 v0; v0.x = bE;  v0.y = s1m;                                 \
        ulonglong2 v1; v1.x = s2m; v1.y = bX;                                  \
        gmp[0] = v0; gmp[1] = v1;                                              \
    }                                                                          \
    gmp += 2;                                                                  \
    ++t;                                                                       \
}

// ---------------- kernel 2: LDS-staged sequential Viterbi DP + backtrace ----------------
__global__ __launch_bounds__(256)
void ctc_dp_kernel(const int* __restrict__ src_size,
                   const int* __restrict__ ys,
                   const int* __restrict__ ylens,
                   const int* __restrict__ blank_p,
                   float* __restrict__ out)
{
    const int b    = blockIdx.x;
    const int tid  = threadIdx.x;          // 256 threads; wave 0 runs the DP
    const int lane = tid & 63;

    const int ss   = src_size[b];
    const int ylen = ylens[b];
    const int plen = 2 * ylen + 1;

    __shared__ __align__(16) float lppL[XMAX * 65];   // 133 KB packed lpp table
    __shared__ ulonglong2 MAB[XMAX][2];               // 16 KB bp masks (for backtrace)
    __shared__ int states[XMAX];
    __shared__ int istS;

    float* gbase = out + TM_OFF + (size_t)b * (YMAX + 1) * XMAX;

    // ---- phase 0: bulk copy the packed table into LDS (all 4 waves) ----
    {
        const float4* src = (const float4*)gbase;
        float4* dst = (float4*)lppL;
        #pragma unroll 4
        for (int i = tid; i < XMAX * 65 / 4; i += 256)
            dst[i] = src[i];
    }
    __syncthreads();

    // ---- phase 1: wave 0 runs the sequential DP (LDS reads only; mask stores -> global) ----
    if (tid < 64) {
        const int  ysv    = ys[b * YMAX + lane];
        const int  ysPrev = dpp_shr1_i(ysv, -1);
        const bool sameO  = (ysv == ysPrev);   // odd-state l-2 transition forbidden

        ulonglong2* gmp = (ulonglong2*)gbase;  // masks at byte t*32 (region is dead)

        float rO[PF], rB[PF];
        #pragma unroll
        for (int k = 0; k < PF; ++k) {
            rO[k] = lppL[k * 65 + lane];
            rB[k] = lppL[k * 65 + 64];
        }

        float aE = (lane == 0) ? 0.0f : LOGZERO;   // alpha[2i]
        float aO = LOGZERO;                        // alpha[2i+1]
        float aX = LOGZERO;                        // alpha[128] (lane 63 meaningful)
        int offO = PF * 65 + lane, offB = PF * 65 + 64;
        int t = 0;

        while (t + PF <= ss) {
            #pragma unroll
            for (int k = 0; k < PF; ++k) DP_BODY(k)
        }
        #pragma unroll
        for (int k = 0; k < PF; ++k) { if (t < ss) DP_BODY(k) }

        // alpha(ss-1) is simply the final register state
        const float s1 = (ylen == YMAX) ? __shfl(aX, 63) : __shfl(aE, ylen);
        const float s2 = __shfl(aO, ylen - 1);
        if (lane == 0) {
            out[SC_OFF + b] = fmaxf(s1, s2);
            out[YL_OFF + b] = (float)(ylen + 1);
            istS = (s1 > s2) ? (plen - 1) : (plen - 2);
        }
    }
    __syncthreads();

    // ---- phase 2: bulk copy masks (16 KB) global -> LDS (all 4 waves) ----
    {
        const float4* src = (const float4*)gbase;
        float4* dst = (float4*)MAB;
        for (int i = tid; i < XMAX * 2; i += 256)
            dst[i] = src[i];
    }
    __syncthreads();

    // ---- phase 3: sequential backtrace (thread 0), 4-deep pipelined LDS reads ----
    if (tid == 0) {
        const int ist = istS;
        int cur = 0;
        ulonglong2 a0 = MAB[XMAX-1][0], b0 = MAB[XMAX-1][1];
        ulonglong2 a1 = MAB[XMAX-2][0], b1 = MAB[XMAX-2][1];
        ulonglong2 a2 = MAB[XMAX-3][0], b2 = MAB[XMAX-3][1];
        ulonglong2 a3 = MAB[XMAX-4][0], b3 = MAB[XMAX-4][1];
        for (int tg = XMAX - 1; tg >= 3; tg -= 4) {
            ulonglong2 na0, na1, na2, na3, nb0, nb1, nb2, nb3;
            const bool more = (tg >= 7);
            if (more) {
                na0 = MAB[tg-4][0]; nb0 = MAB[tg-4][1];
                na1 = MAB[tg-5][0]; nb1 = MAB[tg-5][1];
                na2 = MAB[tg-6][0]; nb2 = MAB[tg-6][1];
                na3 = MAB[tg-7][0]; nb3 = MAB[tg-7][1];
            }
            BT(tg,     a0, b0);
            BT(tg - 1, a1, b1);
            BT(tg - 2, a2, b2);
            BT(tg - 3, a3, b3);
            if (more) {
                a0 = na0; b0 = nb0; a1 = na1; b1 = nb1;
                a2 = na2; b2 = nb2; a3 = na3; b3 = nb3;
            }
        }
    }
    __syncthreads();

    // ---- phase 4: states -> global scratch for the epilogue kernel ----
    {
        int* gst = (int*)gbase + 4096;     // byte offset 16384
        for (int i = tid; i < XMAX; i += 256)
            gst[i] = states[i];
    }
}

// ---------------- kernel 3: epilogue (labels, collapse, trig, trigger mask) ----------------
__global__ __launch_bounds__(256)
void ctc_epilogue_kernel(const int* __restrict__ src_size,
                         const int* __restrict__ ys,
                         const int* __restrict__ blank_p,
                         float* __restrict__ out)
{
    const int b    = blockIdx.x;
    const int tid  = threadIdx.x;
    const int lane = tid & 63;

    const int blank = blank_p[0];
    const int ss    = src_size[b];

    __shared__ int stL[XMAX];
    __shared__ int trig[XMAX];
    __shared__ int ysL[YMAX];

    float* gbase = out + TM_OFF + (size_t)b * (YMAX + 1) * XMAX;
    const int* gst = (const int*)gbase + 4096;

    if (tid < YMAX) ysL[tid] = ys[b * YMAX + tid];
    for (int i = tid; i < XMAX; i += 256) stL[i] = gst[i];
    __syncthreads();

    // ---- wave 0: states -> labels, collapse, aligned_seq, trig scan ----
    if (tid < 64) {
        const int t8 = lane * 8;
        int sq[8];
        #pragma unroll
        for (int j = 0; j < 8; ++j) {
            const int st = stL[t8 + j];
            sq[j] = (st & 1) ? ysL[st >> 1] : blank;
        }
        int prevLast = __shfl_up(sq[7], 1);
        if (lane == 0) prevLast = 0;

        int cl[8];
        #pragma unroll
        for (int j = 0; j < 8; ++j) {
            const int pv = j ? sq[j - 1] : prevLast;
            cl[j] = (sq[j] == pv) ? 0 : sq[j];
        }

        {   // aligned_seq out
            float* as = out + AS_OFF + (size_t)b * XMAX + t8;
            float4 o0, o1;
            o0.x = (float)cl[0]; o0.y = (float)cl[1]; o0.z = (float)cl[2]; o0.w = (float)cl[3];
            o1.x = (float)cl[4]; o1.y = (float)cl[5]; o1.z = (float)cl[6]; o1.w = (float)cl[7];
            *(float4*)as = o0; *((float4*)as + 1) = o1;
        }

        // trig[t] = inclusive cumsum of shifted collapsed != blank
        int cnt = 0;
        #pragma unroll
        for (int j = 0; j < 8; ++j) cnt += (cl[j] != blank);
        int x = cnt;
        #pragma unroll
        for (int d = 1; d < 64; d <<= 1) {
            const int y = __shfl_up(x, d);
            if (lane >= d) x += y;
        }
        int run = x - cnt + ((0 != blank) ? 1 : 0);
        #pragma unroll
        for (int j = 0; j < 8; ++j) {
            trig[t8 + j] = run;
            run += (cl[j] != blank);
        }
    }
    __syncthreads();

    // ---- all 256: trigger mask overwrites the scratch region ----
    float* tm = gbase;
    for (int i4 = tid * 4; i4 < (YMAX + 1) * XMAX; i4 += 256 * 4) {
        const int y  = i4 >> 9;
        const int t0 = i4 & (XMAX - 1);
        const int4 tg4 = *(const int4*)&trig[t0];
        float4 v;
        if (y == YMAX) {
            v.x = ((tg4.x == YMAX && (t0 + 0) < ss) || (t0 + 0) == ss - 1) ? 1.0f : 0.0f;
            v.y = ((tg4.y == YMAX && (t0 + 1) < ss) || (t0 + 1) == ss - 1) ? 1.0f : 0.0f;
            v.z = ((tg4.z == YMAX && (t0 + 2) < ss) || (t0 + 2) == ss - 1) ? 1.0f : 0.0f;
            v.w = ((tg4.w == YMAX && (t0 + 3) < ss) || (t0 + 3) == ss - 1) ? 1.0f : 0.0f;
        } else {
            v.x = (tg4.x == y) ? 1.0f : 0.0f;
            v.y = (tg4.y == y) ? 1.0f : 0.0f;
            v.z = (tg4.z == y) ? 1.0f : 0.0f;
            v.w = (tg4.w == y) ? 1.0f : 0.0f;
        }
        *(float4*)(tm + i4) = v;
    }
}

extern "C" void kernel_launch(void* const* d_in, const int* in_sizes, int n_in,
                              void* d_out, int out_size, void* d_ws, size_t ws_size,
                              hipStream_t stream) {
    (void)in_sizes; (void)n_in; (void)d_ws; (void)ws_size; (void)out_size;
    const float* ctc      = (const float*)d_in[0];
    // d_in[1] = src_mask — derivable from src_size, unused
    const int*   src_size = (const int*)d_in[2];
    const int*   ys       = (const int*)d_in[3];
    const int*   ylens    = (const int*)d_in[4];
    const int*   blank    = (const int*)d_in[5];
    float*       out      = (float*)d_out;

    dim3 g1(XMAX / TCH, BS);
    gather_kernel<<<g1, 64, 0, stream>>>(ctc, ys, blank, out);
    ctc_dp_kernel<<<BS, 256, 0, stream>>>(src_size, ys, ylens, blank, out);
    ctc_epilogue_kernel<<<BS, 256, 0, stream>>>(src_size, ys, blank, out);
}